// Round 15
// baseline (75.955 us; speedup 1.0000x reference)
//
#include <hip/hip_runtime.h>
#include <hip/hip_bf16.h>

// ---- problem constants ----
#define B_IMG   128
#define CH      3
#define HW      224
#define NPATCH  196          // tokens per image
#define TOKENS  25088        // B_IMG * NPATCH
#define PATCH   16
#define FDIM    768          // C*P*P (K of the GEMM)
#define DDIM    768          // output embed dim (N of the GEMM)
#define TOKELEMS ((size_t)TOKENS * FDIM)
#define OUT_TOKENS ((size_t)TOKENS * DDIM)     // positions follow in d_out

// brick = (tile16, kt32): 512 shorts = 1KB. Gather: 1568*24 = 37632 bricks;
// W: 48*24 = 1152 bricks. One WAVE per brick -> 1KB coalesced store.
#define GATHER_BRICK_BLOCKS (37632 / 4)   // 9408
#define W_BRICK_BLOCKS      (1152 / 4)    // 288

typedef short short8 __attribute__((ext_vector_type(8)));
typedef float f32x4  __attribute__((ext_vector_type(4)));

static __device__ __forceinline__ unsigned short f2bf(float v) {
  unsigned u = __float_as_uint(v);
  unsigned r = u + 0x7fffu + ((u >> 16) & 1u);
  return (unsigned short)(r >> 16);
}

static __device__ __forceinline__ void gload16(const short* g, short* l) {
  __builtin_amdgcn_global_load_lds(
      (const __attribute__((address_space(1))) void*)g,
      (__attribute__((address_space(3))) void*)l,
      16, 0, 0);
}

// ---- kernel 1: gather + W-convert into FRAGMENT-MAJOR bricks (R13 verbatim) ----
// Brick layout (shorts): PF[brick*512 + (lg*16+lr)*8 + e]
//   brick = tile16*24 + kt;  row = tile16*16 + lr;  k = kt*32 + lg*8 + e.
// One WAVE builds one brick -> the store is exactly 64x16B = 1KB contiguous.
__global__ __launch_bounds__(256) void prep_kernel(
    const float* __restrict__ x, const int* __restrict__ ys,
    const int* __restrict__ xs, const float* __restrict__ W,
    short* __restrict__ PF, short* __restrict__ WF,
    float* __restrict__ pos) {
  const int w  = threadIdx.x >> 6;
  const int l  = threadIdx.x & 63;
  const int lr = l & 15;
  const int lg = l >> 4;
  const int k8rem = lg & 3;              // k8 = kt*4 + lg

  if (blockIdx.x < GATHER_BRICK_BLOCKS) {
    const int brick  = blockIdx.x * 4 + w;      // 0..37631
    const int tile16 = brick / 24;
    const int kt     = brick - tile16 * 24;
    const int tok    = tile16 * 16 + lr;
    const int b      = tok / NPATCH;
    const int y      = ys[tok];
    const int xc     = xs[tok];
    const int k8     = kt * 4 + k8rem;          // 0..95
    const int c      = k8 >> 5;
    const int rem    = k8 & 31;
    const int py     = rem >> 1;
    const int px0    = (rem & 1) * 8;
    const float* src = x + (size_t)(b * CH + c) * (HW * HW) +
                       (size_t)(y + py) * HW + xc + px0;
    float4 v0 = *(const float4*)src;
    float4 v1 = *(const float4*)(src + 4);
    short8 o;
    o[0] = (short)f2bf(v0.x); o[1] = (short)f2bf(v0.y);
    o[2] = (short)f2bf(v0.z); o[3] = (short)f2bf(v0.w);
    o[4] = (short)f2bf(v1.x); o[5] = (short)f2bf(v1.y);
    o[6] = (short)f2bf(v1.z); o[7] = (short)f2bf(v1.w);
    *(short8*)&PF[(size_t)brick * 512 + l * 8] = o;   // wave: 1KB contiguous
    if (kt == 0 && lg == 0) {
      pos[(size_t)tok * 2]     = (float)y;
      pos[(size_t)tok * 2 + 1] = (float)xc;
    }
  } else {
    const int brick  = (blockIdx.x - GATHER_BRICK_BLOCKS) * 4 + w;  // 0..1151
    const int tile16 = brick / 24;
    const int kt     = brick - tile16 * 24;
    const int n      = tile16 * 16 + lr;
    const int k8     = kt * 4 + k8rem;
    const float* src = W + (size_t)n * FDIM + k8 * 8;
    float4 v0 = *(const float4*)src;
    float4 v1 = *(const float4*)(src + 4);
    short8 o;
    o[0] = (short)f2bf(v0.x); o[1] = (short)f2bf(v0.y);
    o[2] = (short)f2bf(v0.z); o[3] = (short)f2bf(v0.w);
    o[4] = (short)f2bf(v1.x); o[5] = (short)f2bf(v1.y);
    o[6] = (short)f2bf(v1.z); o[7] = (short)f2bf(v1.w);
    *(short8*)&WF[(size_t)brick * 512 + l * 8] = o;
  }
}

// ---- kernel 2: hybrid GEMM — A shared via LDS (ring-3), B register-direct ----
// R14 model: GEMM is global-load-path bound (~32B/cyc/CU; 925MB -> 47us
// predicted, 50 measured). Block = 4 waves sharing ONE 128-row A panel:
// A staged to LDS once per block-step (8KB) instead of 4x through registers;
// B (4KB/wave) stays register-direct. Global bytes 925 -> 339MB.
// Wave job = 128x64 (acc 8x4, 32 MFMA/step). Ring-3 LDS, ONE barrier/step,
// counted vmcnt(6): at step-s pre-MFMA the outstanding ledger (oldest first)
// is [B(s)4, A(s+1)2, B(s+1)4, A(s+2)2] = 12 -> vmcnt(6) forces B(s)+A(s+1);
// A(s+1)-complete-before-barrier gives cross-wave LDS safety; the step's
// ds_reads retire pre-barrier via their MFMA lgkm dependencies.
__global__ __launch_bounds__(256) void gemm_kernel(
    const short* __restrict__ PF,   // fragment-major patches
    const short* __restrict__ WF,   // fragment-major W
    const float* __restrict__ bias,
    float* __restrict__ C) {
  __shared__ short Ab[3][8 * 512];   // 3 ring bufs x 8 bricks x 1KB = 24KB

  const int tid = threadIdx.x;
  const int w   = tid >> 6;      // 0..3 : N quarter of the block's 256 cols
  const int l   = tid & 63;
  const int lr  = l & 15;
  const int lg  = l >> 4;

  // bijective XCD swizzle, 588 blocks = 4 chunks of 74 + 4 of 73 (m204).
  // 3 consecutive nid share mtB -> A panel L2-local per XCD.
  const int id   = blockIdx.x;
  const int xcd  = id & 7;
  const int chnk = id >> 3;
  const int nid  = (xcd < 4 ? xcd * 74 : 296 + (xcd - 4) * 73) + chnk;
  const int mtB  = nid / 3;          // 196 panels of 128 rows
  const int ntg  = nid - mtB * 3;    // 3 col-groups of 256
  const int m0   = mtB * 128;
  const int n0   = ntg * 256 + w * 64;

  // B bricks (per wave): 4 tiles of 16 cols
  const short* pB = WF + (size_t)(n0 >> 4) * 24 * 512 + l * 8;
  // A stage source: wave w stages panel bricks 2w, 2w+1 (per-lane source)
  const short* pAs = PF + (size_t)(mtB * 8 + w * 2) * 24 * 512 + l * 8;
  const int ldst = (w * 2) * 512;    // LDS dest (shorts), wave-uniform

  float bs4[4];
#pragma unroll
  for (int ni = 0; ni < 4; ++ni) bs4[ni] = bias[n0 + ni * 16 + lr];
#pragma unroll
  for (int ni = 0; ni < 4; ++ni) asm volatile("" : "+v"(bs4[ni]));

  f32x4 acc[8][4];
  const f32x4 z = {0.f, 0.f, 0.f, 0.f};
#pragma unroll
  for (int mi = 0; mi < 8; ++mi)
#pragma unroll
    for (int ni = 0; ni < 4; ++ni) acc[mi][ni] = z;

  short8 B0[4], B1[4];   // two named B sets (rule #20)

#define LOADB(BR, KT)                                                      \
  do {                                                                     \
    _Pragma("unroll")                                                      \
    for (int i = 0; i < 4; ++i)                                            \
      BR[i] = *(const short8*)(pB + (size_t)i * 12288 + (size_t)(KT) * 512);\
  } while (0)

#define STAGEA(SLOT, KT)                                                   \
  do {                                                                     \
    gload16(pAs + (size_t)(KT) * 512, &Ab[(SLOT)][ldst]);                  \
    gload16(pAs + 12288 + (size_t)(KT) * 512, &Ab[(SLOT)][ldst + 512]);    \
  } while (0)

// one pipeline step. BUF = s%3, STG = (s+2)%3, BR = B set for s, KT2 = s+2.
#define GSTEP(BUF, STG, BR, KT2, DOSTG, DOB, VMN)                          \
  do {                                                                     \
    short8 a_[4];                                                          \
    _Pragma("unroll")                                                      \
    for (int i = 0; i < 4; ++i)                                            \
      a_[i] = *(const short8*)&Ab[(BUF)][i * 512 + l * 8];                 \
    if (DOSTG) STAGEA(STG, KT2);                                           \
    asm volatile("s_waitcnt vmcnt(" #VMN ")" ::: "memory");                \
    __builtin_amdgcn_sched_barrier(0);                                     \
    __builtin_amdgcn_s_setprio(1);                                         \
    _Pragma("unroll")                                                      \
    for (int mi = 0; mi < 4; ++mi)                                         \
      _Pragma("unroll")                                                    \
      for (int ni = 0; ni < 4; ++ni)                                       \
        acc[mi][ni] = __builtin_amdgcn_mfma_f32_16x16x32_bf16(             \
            a_[mi], BR[ni], acc[mi][ni], 0, 0, 0);                         \
    __builtin_amdgcn_s_setprio(0);                                         \
    short8 a2_[4];                                                         \
    _Pragma("unroll")                                                      \
    for (int i = 0; i < 4; ++i)                                            \
      a2_[i] = *(const short8*)&Ab[(BUF)][(4 + i) * 512 + l * 8];          \
    __builtin_amdgcn_s_setprio(1);                                         \
    _Pragma("unroll")                                                      \
    for (int mi = 0; mi < 4; ++mi)                                         \
      _Pragma("unroll")                                                    \
      for (int ni = 0; ni < 4; ++ni)                                       \
        acc[4 + mi][ni] = __builtin_amdgcn_mfma_f32_16x16x32_bf16(         \
            a2_[mi], BR[ni], acc[4 + mi][ni], 0, 0, 0);                    \
    __builtin_amdgcn_s_setprio(0);                                         \
    if (DOB) LOADB(BR, KT2);                                               \
    __builtin_amdgcn_sched_barrier(0);                                     \
    __builtin_amdgcn_s_barrier();                                          \
  } while (0)

  // prologue: A0,B0,A1,B1 in flight (12 ops); force A0, keep rest flying
  STAGEA(0, 0);
  LOADB(B0, 0);
  STAGEA(1, 1);
  LOADB(B1, 1);
  asm volatile("s_waitcnt vmcnt(10)" ::: "memory");
  __builtin_amdgcn_sched_barrier(0);
  __builtin_amdgcn_s_barrier();

  // steady: steps 0..17 (3 macro-periods of 6; buf/Bset indices static)
#pragma unroll 1
  for (int p = 0; p < 3; ++p) {
    const int s0 = p * 6;
    GSTEP(0, 2, B0, s0 + 2, 1, 1, 6);
    GSTEP(1, 0, B1, s0 + 3, 1, 1, 6);
    GSTEP(2, 1, B0, s0 + 4, 1, 1, 6);
    GSTEP(0, 2, B1, s0 + 5, 1, 1, 6);
    GSTEP(1, 0, B0, s0 + 6, 1, 1, 6);
    GSTEP(2, 1, B1, s0 + 7, 1, 1, 6);
  }
  // peeled tail: steps 18..23 with exact drain counts
  GSTEP(0, 2, B0, 20, 1, 1, 6);
  GSTEP(1, 0, B1, 21, 1, 1, 6);
  GSTEP(2, 1, B0, 22, 1, 1, 6);
  GSTEP(0, 2, B1, 23, 1, 1, 6);
  GSTEP(1, 0, B0, 24, 0, 0, 4);   // forces A23 (leaves B23 in flight)
  GSTEP(2, 1, B1, 25, 0, 0, 0);   // forces B23

  // epilogue: C/D layout col = lane&15, row = (lane>>4)*4 + j
#pragma unroll
  for (int ni = 0; ni < 4; ++ni) {
    const int col = n0 + ni * 16 + lr;
#pragma unroll
    for (int mi = 0; mi < 8; ++mi) {
      const int row = m0 + mi * 16 + lg * 4;
      const f32x4 v = acc[mi][ni];
#pragma unroll
      for (int j = 0; j < 4; ++j)
        C[(size_t)(row + j) * DDIM + col] = v[j] + bs4[ni];
    }
  }
#undef LOADB
#undef STAGEA
#undef GSTEP
}

// ---- fallback (ws too small): naive fused f32, correct but slow ----
__global__ __launch_bounds__(256) void naive_kernel(
    const float* __restrict__ x, const int* __restrict__ ys,
    const int* __restrict__ xs, const float* __restrict__ W,
    const float* __restrict__ bias, float* __restrict__ out) {
  __shared__ float prow[FDIM];
  const int tok = blockIdx.x;
  const int t   = threadIdx.x;
  const int b   = tok / NPATCH;
  const int y   = ys[tok];
  const int xc  = xs[tok];
  for (int i = t; i < FDIM; i += 256) {
    int c = i >> 8, rem = i & 255, py = rem >> 4, px = rem & 15;
    prow[i] = x[((size_t)(b * CH + c) * HW + y + py) * HW + xc + px];
  }
  __syncthreads();
  for (int dd = 0; dd < 3; ++dd) {
    const int d = t + dd * 256;
    float s = bias[d];
    const float4* wr = (const float4*)&W[(size_t)d * FDIM];
    const float4* pr = (const float4*)prow;
    for (int f4 = 0; f4 < FDIM / 4; ++f4) {
      float4 wv = wr[f4];
      float4 pv = pr[f4];
      s += wv.x * pv.x + wv.y * pv.y + wv.z * pv.z + wv.w * pv.w;
    }
    out[(size_t)tok * DDIM + d] = s;
  }
  if (t == 0) {
    float* pos = out + OUT_TOKENS;
    pos[(size_t)tok * 2]     = (float)y;
    pos[(size_t)tok * 2 + 1] = (float)xc;
  }
}

extern "C" void kernel_launch(void* const* d_in, const int* in_sizes, int n_in,
                              void* d_out, int out_size, void* d_ws, size_t ws_size,
                              hipStream_t stream) {
  const float* x    = (const float*)d_in[0];
  const int*   ys   = (const int*)d_in[1];
  const int*   xs   = (const int*)d_in[2];
  const float* W    = (const float*)d_in[3];
  const float* bias = (const float*)d_in[4];
  float* out = (float*)d_out;
  float* pos = out + OUT_TOKENS;

  const size_t w_bytes = (size_t)DDIM * FDIM * 2;   // WF: 1,179,648
  const size_t p_bytes = TOKELEMS * 2;              // PF: 38,535,168
  if (ws_size >= w_bytes + p_bytes) {
    short* WF = (short*)d_ws;
    short* PF = (short*)d_ws + (size_t)DDIM * FDIM;
    prep_kernel<<<GATHER_BRICK_BLOCKS + W_BRICK_BLOCKS, 256, 0, stream>>>(
        x, ys, xs, W, PF, WF, pos);
    gemm_kernel<<<588, 256, 0, stream>>>(PF, WF, bias, out);
  } else {
    naive_kernel<<<TOKENS, 256, 0, stream>>>(x, ys, xs, W, bias, out);
  }
}